// Round 3
// baseline (733.812 us; speedup 1.0000x reference)
//
#include <hip/hip_runtime.h>
#include <hip/hip_bf16.h>
#include <math.h>

// Problem constants
#define BB 4
#define NSEQ 4096
#define DD 1024
#define HH 16
#define HD 64
#define MROWS (BB * NSEQ)   // 16384

typedef __attribute__((ext_vector_type(8))) short short8;
typedef float v4f __attribute__((ext_vector_type(4)));
typedef unsigned short u16;

__device__ __constant__ int SHIFTS[24] = {0,1,2,3,4,6,8,12,16,24,32,48,64,96,128,192,256,384,512,768,1024,1536,2048,3072};

__device__ inline u16 f2bf(float f) {
    unsigned u = __float_as_uint(f);
    unsigned r = u + 0x7fffu + ((u >> 16) & 1u);
    return (u16)(r >> 16);
}
__device__ inline float bf2f(u16 h) {
    return __uint_as_float(((unsigned)h) << 16);
}

// ---------------- prep: merged 24-tap coef table per head, coupling softmax, skip sigmoid ----------------
__global__ void prep_kernel(const float* __restrict__ scale_gain, const float* __restrict__ skip_w,
                            const float* __restrict__ coupling, float* __restrict__ coefTab,
                            float* __restrict__ coupS, float* __restrict__ swbuf) {
    const float D4T[4] = {0.4829629131445341f, 0.8365163037378079f, 0.2241438680420134f, -0.1294095225512604f};
    int t = threadIdx.x;
    if (t < 2) swbuf[t] = 1.0f / (1.0f + expf(-skip_w[t]));
    if (t < 16) {
        // coupling row softmax
        float m = -1e30f;
        for (int j = 0; j < 16; j++) m = fmaxf(m, coupling[t * 16 + j]);
        float s = 0.f, e[16];
        for (int j = 0; j < 16; j++) { e[j] = expf(coupling[t * 16 + j] - m); s += e[j]; }
        for (int j = 0; j < 16; j++) coupS[t * 16 + j] = e[j] / s;
        // gains softmax over 11 scales for head t
        float g[11];
        m = -1e30f;
        for (int j = 0; j < 11; j++) m = fmaxf(m, scale_gain[j * 16 + t]);
        s = 0.f;
        for (int j = 0; j < 11; j++) { g[j] = expf(scale_gain[j * 16 + t] - m); s += g[j]; }
        for (int j = 0; j < 11; j++) g[j] /= s;
        float cf[24];
        for (int i = 0; i < 24; i++) cf[i] = 0.f;
        for (int j = 0; j < 11; j++) {
            int d = 1 << j;
            for (int tt = 0; tt < 4; tt++) {
                int sh = (3 - tt) * d;
                for (int i = 0; i < 24; i++) {
                    if (SHIFTS[i] == sh) { cf[i] += g[j] * D4T[tt]; break; }
                }
            }
        }
        for (int i = 0; i < 24; i++) coefTab[t * 24 + i] = cf[i];
    }
}

// ---------------- bfuse[n] = bqkv_q @ Wgate + bgate (fp32) ----------------
__global__ void bfuse_kernel(const float* __restrict__ bqkv, const float* __restrict__ Wgate,
                             const float* __restrict__ bgate, float* __restrict__ bfuse) {
    int n = blockIdx.x * 256 + threadIdx.x;    // 0..1023
    float s = bgate[n];
    for (int j = 0; j < 1024; j++)
        s += bqkv[j] * Wgate[j * 1024 + n];
    bfuse[n] = s;
}

// ---------------- transpose + cast: W fp32 [rows][ldw] -> WT bf16 [cols][ldt] ----------------
__global__ __launch_bounds__(256) void transpose_cast(const float* __restrict__ W, long ldw,
                                                      u16* __restrict__ WT, long ldt) {
    __shared__ float tile[32][33];
    int tx = threadIdx.x, ty = threadIdx.y;    // 32 x 8
    long x = (long)blockIdx.x * 32 + tx;       // source col
    long y0 = (long)blockIdx.y * 32;           // source row base
    for (int r = 0; r < 32; r += 8)
        tile[ty + r][tx] = W[(y0 + ty + r) * ldw + x];
    __syncthreads();
    for (int r = 0; r < 32; r += 8)
        WT[((long)blockIdx.x * 32 + ty + r) * ldt + y0 + tx] = f2bf(tile[tx][ty + r]);
}

// ---------------- cast q-columns of Wqkv (fp32, ld 3072) -> WqC bf16 [1024][1024] ----------------
__global__ __launch_bounds__(256) void cast_q_kernel(const float* __restrict__ Wqkv, u16* __restrict__ WqC) {
    long i = ((long)blockIdx.x * 256 + threadIdx.x) * 4;   // element quad in [0, 1024*1024)
    int row = (int)(i >> 10);
    int col = (int)(i & 1023);
    float4 f = *(const float4*)&Wqkv[(long)row * 3072 + col];
    ushort4 o;
    o.x = f2bf(f.x); o.y = f2bf(f.y); o.z = f2bf(f.z); o.w = f2bf(f.w);
    *(ushort4*)&WqC[i] = o;
}

// ---------------- GEMM: C[M,N] = A[M,K] * BT[N,K]^T + bias ----------------
// CMODE: 0 = fp32 out, 1 = bf16 out, 2 = sigmoid -> bf16 out
// ABF16: A is bf16 (else fp32, cast during staging)
template <int CMODE, bool ABF16>
__global__ __launch_bounds__(256) void gemm_kernel(const void* __restrict__ Aptr, long lda,
                                                   const u16* __restrict__ BT, long ldb, int K,
                                                   const float* __restrict__ bias,
                                                   void* __restrict__ Cptr, long ldc) {
    __shared__ u16 As[128 * 40];
    __shared__ u16 Bs[128 * 40];
    int tid = threadIdx.x;
    int wave = tid >> 6, lane = tid & 63;
    int wm = wave >> 1, wn = wave & 1;        // 2x2 wave grid, each wave 64x64
    int lrow = lane & 15, kq = lane >> 4;
    long m0 = (long)blockIdx.y * 128, n0 = (long)blockIdx.x * 128;
    v4f acc[4][4];
#pragma unroll
    for (int i = 0; i < 4; i++)
#pragma unroll
        for (int j = 0; j < 4; j++) acc[i][j] = (v4f){0.f, 0.f, 0.f, 0.f};

    int r = tid >> 1, halfsel = tid & 1;      // 2 threads/row, 16 elems each (BK=32)

    for (int k0 = 0; k0 < K; k0 += 32) {
        if (ABF16) {
            const u16* Ap = (const u16*)Aptr + (m0 + r) * lda + k0 + halfsel * 16;
            uint4 u0 = *(const uint4*)Ap;
            uint4 u1 = *(const uint4*)(Ap + 8);
            *(uint4*)&As[r * 40 + halfsel * 16] = u0;
            *(uint4*)&As[r * 40 + halfsel * 16 + 8] = u1;
        } else {
            const float* Ap = (const float*)Aptr + (m0 + r) * lda + k0 + halfsel * 16;
            float f[16];
#pragma unroll
            for (int i = 0; i < 4; i++) {
                float4 tt = *(const float4*)(Ap + i * 4);
                f[i * 4 + 0] = tt.x; f[i * 4 + 1] = tt.y; f[i * 4 + 2] = tt.z; f[i * 4 + 3] = tt.w;
            }
            unsigned pk[8];
#pragma unroll
            for (int i = 0; i < 8; i++)
                pk[i] = (unsigned)f2bf(f[2 * i]) | ((unsigned)f2bf(f[2 * i + 1]) << 16);
            uint4* dst = (uint4*)&As[r * 40 + halfsel * 16];
            dst[0] = make_uint4(pk[0], pk[1], pk[2], pk[3]);
            dst[1] = make_uint4(pk[4], pk[5], pk[6], pk[7]);
        }
        {
            const u16* Bp = BT + (n0 + r) * ldb + k0 + halfsel * 16;
            uint4 u0 = *(const uint4*)Bp;
            uint4 u1 = *(const uint4*)(Bp + 8);
            *(uint4*)&Bs[r * 40 + halfsel * 16] = u0;
            *(uint4*)&Bs[r * 40 + halfsel * 16 + 8] = u1;
        }
        __syncthreads();

        short8 af[4], bfr[4];
#pragma unroll
        for (int i = 0; i < 4; i++)
            af[i] = *(const short8*)&As[(wm * 64 + i * 16 + lrow) * 40 + kq * 8];
#pragma unroll
        for (int i = 0; i < 4; i++)
            bfr[i] = *(const short8*)&Bs[(wn * 64 + i * 16 + lrow) * 40 + kq * 8];
#pragma unroll
        for (int im = 0; im < 4; im++)
#pragma unroll
            for (int in = 0; in < 4; in++)
                acc[im][in] = __builtin_amdgcn_mfma_f32_16x16x32_bf16(af[im], bfr[in], acc[im][in], 0, 0, 0);
        __syncthreads();
    }

#pragma unroll
    for (int im = 0; im < 4; im++) {
#pragma unroll
        for (int in = 0; in < 4; in++) {
            long row = m0 + wm * 64 + im * 16 + kq * 4;
            long col = n0 + wn * 64 + in * 16 + lrow;
            float bv = bias ? bias[col] : 0.f;
#pragma unroll
            for (int i = 0; i < 4; i++) {
                float val = acc[im][in][i] + bv;
                long idx = (row + i) * ldc + col;
                if (CMODE == 0) {
                    ((float*)Cptr)[idx] = val;
                } else if (CMODE == 1) {
                    ((u16*)Cptr)[idx] = f2bf(val);
                } else {
                    float sg = 1.0f / (1.0f + expf(-val));
                    ((u16*)Cptr)[idx] = f2bf(sg);
                }
            }
        }
    }
}

// ---------------- kmag[b][h][n] = ||k(row,h)|| ----------------
__global__ __launch_bounds__(256) void kmag_kernel(const u16* __restrict__ kv, float* __restrict__ kmag) {
    int tid = threadIdx.x;
    int wave = tid >> 6, lane = tid & 63;
    long gid = (long)blockIdx.x * 4 + wave;   // 0 .. 16384*16-1
    int row = (int)(gid >> 4);
    int h = (int)(gid & 15);
    float kvl = bf2f(kv[(long)row * 2048 + h * 64 + lane]);
    float ss = kvl * kvl;
#pragma unroll
    for (int m = 32; m > 0; m >>= 1) ss += __shfl_xor(ss, m, 64);
    if (lane == 0) {
        int b = row >> 12;
        int n = row & 4095;
        kmag[((long)b * HH + h) * NSEQ + n] = sqrtf(ss);
    }
}

// ---------------- pyramid: 24-tap merged dilated causal conv; field = v*kmag on the fly ----------------
__global__ __launch_bounds__(512) void pyramid_kernel(const u16* __restrict__ kv,
                                                      const float* __restrict__ kmag,
                                                      const float* __restrict__ coefTab,
                                                      u16* __restrict__ accp) {
    __shared__ u16 lds4[NSEQ * 4];  // 32KB: 4096 rows x 4 channels, bf16
    int blk = blockIdx.x;
    int bh = blk >> 4;       // 0..63 : b*16+h
    int cg = blk & 15;       // channel group of 4
    int hd0 = cg * 4;
    int b = bh >> 4, h = bh & 15;
    int tid = threadIdx.x;

    float cf[24];
#pragma unroll
    for (int i = 0; i < 24; i++) cf[i] = coefTab[h * 24 + i];

    const u16* vsrc = kv + 1024 + h * 64 + hd0;
    const float* km = kmag + (long)bh * NSEQ;
#pragma unroll
    for (int i = 0; i < 8; i++) {
        int n = tid + i * 512;
        ushort4 vv = *(const ushort4*)&vsrc[((long)b * NSEQ + n) * 2048];
        float g = km[n];
        ushort4 fo;
        fo.x = f2bf(bf2f(vv.x) * g);
        fo.y = f2bf(bf2f(vv.y) * g);
        fo.z = f2bf(bf2f(vv.z) * g);
        fo.w = f2bf(bf2f(vv.w) * g);
        *(ushort4*)&lds4[n * 4] = fo;
    }
    __syncthreads();

    u16* dst = accp + (long)bh * NSEQ * HD + hd0;
    for (int i = 0; i < 8; i++) {
        int n = tid + i * 512;
        float ax = 0.f, ay = 0.f, az = 0.f, aw = 0.f;
#pragma unroll
        for (int tp = 0; tp < 24; tp++) {
            int s = SHIFTS[tp];
            if (n >= s) {
                const ushort4 f = *(const ushort4*)&lds4[(n - s) * 4];
                float c = cf[tp];
                ax += c * bf2f(f.x); ay += c * bf2f(f.y);
                az += c * bf2f(f.z); aw += c * bf2f(f.w);
            }
        }
        ushort4 o;
        o.x = f2bf(ax); o.y = f2bf(ay); o.z = f2bf(az); o.w = f2bf(aw);
        *(ushort4*)&dst[(long)n * HD] = o;
    }
}

// ---------------- couple: sparse skips + head coupling + gate -> A3 bf16 ----------------
__global__ __launch_bounds__(256) void couple_kernel(const u16* __restrict__ accp,
                                                     const u16* __restrict__ gate,
                                                     const float* __restrict__ coupS,
                                                     const float* __restrict__ swbuf,
                                                     u16* __restrict__ A3) {
    __shared__ float tmp[DD];
    __shared__ float cp[256];
    int row = blockIdx.x;
    int b = row >> 12;
    int n = row & 4095;
    int tid = threadIdx.x;
    float sw0 = swbuf[0], sw1 = swbuf[1];
    cp[tid] = coupS[tid];

    int e = tid * 4;
    int j = e >> 6;      // head
    int hd = e & 63;
    const u16* base = accp + (((long)b * HH + j) * NSEQ + n) * HD + hd;
    ushort4 v0 = *(const ushort4*)base;
    float vx = bf2f(v0.x), vy = bf2f(v0.y), vz = bf2f(v0.z), vw = bf2f(v0.w);
    if (n >= 512) {
        ushort4 s1 = *(const ushort4*)(base - 512 * HD);
        vx += sw0 * bf2f(s1.x); vy += sw0 * bf2f(s1.y);
        vz += sw0 * bf2f(s1.z); vw += sw0 * bf2f(s1.w);
    }
    if (n >= 1024) {
        ushort4 s2 = *(const ushort4*)(base - 1024 * HD);
        vx += sw1 * bf2f(s2.x); vy += sw1 * bf2f(s2.y);
        vz += sw1 * bf2f(s2.z); vw += sw1 * bf2f(s2.w);
    }
    tmp[e] = vx; tmp[e + 1] = vy; tmp[e + 2] = vz; tmp[e + 3] = vw;
    __syncthreads();

    float ox = 0.f, oy = 0.f, oz = 0.f, ow = 0.f;
#pragma unroll
    for (int jj = 0; jj < 16; jj++) {
        float c = cp[j * 16 + jj];
        ox += c * tmp[jj * 64 + hd];
        oy += c * tmp[jj * 64 + hd + 1];
        oz += c * tmp[jj * 64 + hd + 2];
        ow += c * tmp[jj * 64 + hd + 3];
    }
    const ushort4 g = *(const ushort4*)&gate[(long)row * DD + e];
    ox *= bf2f(g.x); oy *= bf2f(g.y); oz *= bf2f(g.z); ow *= bf2f(g.w);
    ushort4 o;
    o.x = f2bf(ox); o.y = f2bf(oy); o.z = f2bf(oz); o.w = f2bf(ow);
    *(ushort4*)&A3[(long)row * DD + e] = o;
}

// ---------------- launch ----------------
extern "C" void kernel_launch(void* const* d_in, const int* in_sizes, int n_in,
                              void* d_out, int out_size, void* d_ws, size_t ws_size,
                              hipStream_t stream) {
    const float* x        = (const float*)d_in[0];   // [16384][1024]
    const float* Wqkv     = (const float*)d_in[1];   // [1024][3072]
    const float* bqkv     = (const float*)d_in[2];   // [3072]
    const float* Wout     = (const float*)d_in[3];   // [1024][1024]
    const float* bout     = (const float*)d_in[4];   // [1024]
    const float* Wgate    = (const float*)d_in[5];   // [1024][1024]
    const float* bgate    = (const float*)d_in[6];   // [1024]
    const float* scale_g  = (const float*)d_in[7];   // [11][16]
    const float* skip_w   = (const float*)d_in[8];   // [2]
    const float* coupling = (const float*)d_in[9];   // [16][16]

    char* ws = (char*)d_ws;
    size_t off = 0;
    auto alloc = [&](size_t bytes) { char* p = ws + off; off += (bytes + 255) & ~(size_t)255; return p; };

    u16*   kv     = (u16*)alloc((size_t)MROWS * 2048 * 2);        // 67.1 MB (k: cols 0..1023, v: 1024..2047)
    u16*   gate   = (u16*)alloc((size_t)MROWS * DD * 2);          // 33.6 MB
    u16*   accp   = (u16*)alloc((size_t)BB * HH * NSEQ * HD * 2); // 33.6 MB
    u16*   WkvT   = (u16*)alloc((size_t)2048 * 1024 * 2);         // 4.2 MB
    u16*   WgateT = (u16*)alloc((size_t)1024 * 1024 * 2);         // 2.1 MB
    u16*   WoutT  = (u16*)alloc((size_t)1024 * 1024 * 2);         // 2.1 MB
    u16*   WfuseT = (u16*)alloc((size_t)1024 * 1024 * 2);         // 2.1 MB
    u16*   WqC    = (u16*)alloc((size_t)1024 * 1024 * 2);         // 2.1 MB
    float* kmag   = (float*)alloc((size_t)BB * HH * NSEQ * 4);    // 1.0 MB
    float* bfuse  = (float*)alloc(1024 * 4);
    float* coefT  = (float*)alloc(16 * 24 * 4);
    float* coupS  = (float*)alloc(256 * 4);
    float* swbuf  = (float*)alloc(2 * 4);
    u16*   A3     = kv;  // alias: kv dead after pyramid_kernel
    // total ~148 MB

    // 1) small prep
    prep_kernel<<<1, 64, 0, stream>>>(scale_g, skip_w, coupling, coefT, coupS, swbuf);
    bfuse_kernel<<<4, 256, 0, stream>>>(bqkv, Wgate, bgate, bfuse);

    // 2) weight transposes/casts (fp32 -> bf16, B^T layout for MFMA)
    transpose_cast<<<dim3(64, 32), dim3(32, 8), 0, stream>>>(Wqkv + 1024, 3072, WkvT, 1024);  // k,v cols
    transpose_cast<<<dim3(32, 32), dim3(32, 8), 0, stream>>>(Wgate, 1024, WgateT, 1024);
    transpose_cast<<<dim3(32, 32), dim3(32, 8), 0, stream>>>(Wout, 1024, WoutT, 1024);
    cast_q_kernel<<<1024, 256, 0, stream>>>(Wqkv, WqC);                                       // q cols, no transpose

    // 3) WfuseT[g][k_in] = sum_j WgateT[g][j] * Wqkv[k_in][j]  (= (Wqkv_q @ Wgate)^T)
    gemm_kernel<1, true><<<dim3(8, 8), 256, 0, stream>>>(WgateT, 1024, WqC, 1024, 1024,
                                                         (const float*)nullptr, WfuseT, 1024);

    // 4) kv = x @ Wqkv_kv + bqkv_kv   (fp32 A, bf16 out, N=2048)
    gemm_kernel<1, false><<<dim3(16, 128), 256, 0, stream>>>(x, 1024, WkvT, 1024, 1024,
                                                             bqkv + 1024, kv, 2048);

    // 5) kmag
    kmag_kernel<<<(MROWS * HH) / 4, 256, 0, stream>>>(kv, kmag);

    // 6) gate = sigmoid(x @ Wfuse + bfuse)  (fp32 A, bf16 out)
    gemm_kernel<2, false><<<dim3(8, 128), 256, 0, stream>>>(x, 1024, WfuseT, 1024, 1024,
                                                            bfuse, gate, 1024);

    // 7) pyramid (field formed on the fly, 24 merged taps) -> accp bf16
    pyramid_kernel<<<BB * HH * 16, 512, 0, stream>>>(kv, kmag, coefT, accp);

    // 8) skips + coupling + gating -> A3 bf16 (aliases kv)
    couple_kernel<<<MROWS, 256, 0, stream>>>(accp, gate, coupS, swbuf, A3);

    // 9) out = A3 @ Wout + bout  (bf16 A, fp32 out)
    gemm_kernel<0, true><<<dim3(8, 128), 256, 0, stream>>>(A3, 1024, WoutT, 1024, 1024,
                                                           bout, (float*)d_out, 1024);
}

// Round 4
// 579.391 us; speedup vs baseline: 1.2665x; 1.2665x over previous
//
#include <hip/hip_runtime.h>
#include <hip/hip_bf16.h>
#include <math.h>

// Problem constants
#define BB 4
#define NSEQ 4096
#define DD 1024
#define HH 16
#define HD 64
#define MROWS (BB * NSEQ)   // 16384

typedef __attribute__((ext_vector_type(8))) short short8;
typedef float v4f __attribute__((ext_vector_type(4)));
typedef unsigned short u16;

typedef __attribute__((address_space(1))) const void gconst_void;
typedef __attribute__((address_space(3))) void lds_void_t;

__device__ __constant__ int SHIFTS[24] = {0,1,2,3,4,6,8,12,16,24,32,48,64,96,128,192,256,384,512,768,1024,1536,2048,3072};

__device__ inline u16 f2bf(float f) {
    unsigned u = __float_as_uint(f);
    unsigned r = u + 0x7fffu + ((u >> 16) & 1u);
    return (u16)(r >> 16);
}
__device__ inline float bf2f(u16 h) {
    return __uint_as_float(((unsigned)h) << 16);
}
__device__ inline void gl2lds16(const u16* g, u16* l) {
    // async global->LDS DMA, 16B per lane; LDS dest = wave-uniform base + lane*16
    __builtin_amdgcn_global_load_lds((gconst_void*)g, (lds_void_t*)l, 16, 0, 0);
}

// ---------------- prep: merged 24-tap coef table per head, coupling softmax, skip sigmoid ----------------
__global__ void prep_kernel(const float* __restrict__ scale_gain, const float* __restrict__ skip_w,
                            const float* __restrict__ coupling, float* __restrict__ coefTab,
                            float* __restrict__ coupS, float* __restrict__ swbuf) {
    const float D4T[4] = {0.4829629131445341f, 0.8365163037378079f, 0.2241438680420134f, -0.1294095225512604f};
    int t = threadIdx.x;
    if (t < 2) swbuf[t] = 1.0f / (1.0f + expf(-skip_w[t]));
    if (t < 16) {
        float m = -1e30f;
        for (int j = 0; j < 16; j++) m = fmaxf(m, coupling[t * 16 + j]);
        float s = 0.f, e[16];
        for (int j = 0; j < 16; j++) { e[j] = expf(coupling[t * 16 + j] - m); s += e[j]; }
        for (int j = 0; j < 16; j++) coupS[t * 16 + j] = e[j] / s;
        float g[11];
        m = -1e30f;
        for (int j = 0; j < 11; j++) m = fmaxf(m, scale_gain[j * 16 + t]);
        s = 0.f;
        for (int j = 0; j < 11; j++) { g[j] = expf(scale_gain[j * 16 + t] - m); s += g[j]; }
        for (int j = 0; j < 11; j++) g[j] /= s;
        float cf[24];
        for (int i = 0; i < 24; i++) cf[i] = 0.f;
        for (int j = 0; j < 11; j++) {
            int d = 1 << j;
            for (int tt = 0; tt < 4; tt++) {
                int sh = (3 - tt) * d;
                for (int i = 0; i < 24; i++) {
                    if (SHIFTS[i] == sh) { cf[i] += g[j] * D4T[tt]; break; }
                }
            }
        }
        for (int i = 0; i < 24; i++) coefTab[t * 24 + i] = cf[i];
    }
}

// ---------------- bfuse[n] = bqkv_q @ Wgate + bgate (fp32), 16-block two-phase ----------------
__global__ __launch_bounds__(256) void bfuse_kernel(const float* __restrict__ bqkv, const float* __restrict__ Wgate,
                                                    const float* __restrict__ bgate, float* __restrict__ bfuse) {
    __shared__ float part[4][64];
    int nloc = threadIdx.x & 63, strip = threadIdx.x >> 6;
    int n = blockIdx.x * 64 + nloc;
    float s = 0.f;
    for (int j = strip * 256; j < strip * 256 + 256; j++)
        s += bqkv[j] * Wgate[(long)j * 1024 + n];
    part[strip][nloc] = s;
    __syncthreads();
    if (strip == 0)
        bfuse[n] = bgate[n] + part[0][nloc] + part[1][nloc] + part[2][nloc] + part[3][nloc];
}

// ---------------- cast x fp32 -> bf16 ----------------
__global__ __launch_bounds__(256) void cast_x_kernel(const float* __restrict__ x, u16* __restrict__ xb) {
    long i = ((long)blockIdx.x * 256 + threadIdx.x) * 8;
    float4 f0 = *(const float4*)&x[i];
    float4 f1 = *(const float4*)&x[i + 4];
    u16 o[8];
    o[0] = f2bf(f0.x); o[1] = f2bf(f0.y); o[2] = f2bf(f0.z); o[3] = f2bf(f0.w);
    o[4] = f2bf(f1.x); o[5] = f2bf(f1.y); o[6] = f2bf(f1.z); o[7] = f2bf(f1.w);
    *(uint4*)&xb[i] = *(uint4*)o;
}

// ---------------- transpose + cast: W fp32 [rows][ldw] -> WT bf16 [cols][ldt] ----------------
__global__ __launch_bounds__(256) void transpose_cast(const float* __restrict__ W, long ldw,
                                                      u16* __restrict__ WT, long ldt) {
    __shared__ float tile[32][33];
    int tx = threadIdx.x, ty = threadIdx.y;    // 32 x 8
    long x = (long)blockIdx.x * 32 + tx;
    long y0 = (long)blockIdx.y * 32;
    for (int r = 0; r < 32; r += 8)
        tile[ty + r][tx] = W[(y0 + ty + r) * ldw + x];
    __syncthreads();
    for (int r = 0; r < 32; r += 8)
        WT[((long)blockIdx.x * 32 + ty + r) * ldt + y0 + tx] = f2bf(tile[tx][ty + r]);
}

// ---------------- cast q-columns of Wqkv (fp32, ld 3072) -> WqC bf16 [1024][1024] ----------------
__global__ __launch_bounds__(256) void cast_q_kernel(const float* __restrict__ Wqkv, u16* __restrict__ WqC) {
    long i = ((long)blockIdx.x * 256 + threadIdx.x) * 4;
    int row = (int)(i >> 10);
    int col = (int)(i & 1023);
    float4 f = *(const float4*)&Wqkv[(long)row * 3072 + col];
    ushort4 o;
    o.x = f2bf(f.x); o.y = f2bf(f.y); o.z = f2bf(f.z); o.w = f2bf(f.w);
    *(ushort4*)&WqC[i] = o;
}

// ---------------- GEMM v2: C[M,N] = A[M,K]*BT[N,K]^T + bias; bf16 in; global_load_lds staging ----------------
// CMODE: 0 = fp32 out, 1 = bf16 out, 2 = sigmoid -> bf16 out
template <int CMODE>
__global__ __launch_bounds__(256) void gemm2(const u16* __restrict__ A, long lda,
                                             const u16* __restrict__ BT, long ldb, int K,
                                             const float* __restrict__ bias,
                                             void* __restrict__ Cptr, long ldc) {
    __shared__ u16 As[128 * 32];   // 8 KB, 64 B/row, column-XOR-swizzled
    __shared__ u16 Bs[128 * 32];
    const int tid = threadIdx.x;
    const int wave = tid >> 6, lane = tid & 63;
    const int wm = wave >> 1, wn = wave & 1;      // 2x2 wave grid, 64x64 per wave
    const int lrow = lane & 15, kq = lane >> 4;
    const long m0 = (long)blockIdx.y * 128, n0 = (long)blockIdx.x * 128;

    // staging: wave stages rows [wave*32, wave*32+32) of A and B, 2 issues each (16 rows/issue).
    // lane i covers (row = base + i/4, seg = (i&3) ^ ((row>>1)&3)): LDS col swizzle for conflict-free frag reads.
    const int r0 = wave * 32 + (lane >> 2);       // issue-0 local row; issue-1 = +16 (same swizzle: (+16>>1)&3==0)
    const int sg = (lane & 3) ^ ((r0 >> 1) & 3);
    const u16* a0 = A + (m0 + r0) * lda + sg * 8;
    const u16* a1 = a0 + 16 * lda;
    const u16* b0 = BT + (n0 + r0) * ldb + sg * 8;
    const u16* b1 = b0 + 16 * ldb;
    u16* la0 = &As[(wave * 32) * 32];
    u16* la1 = &As[(wave * 32 + 16) * 32];
    u16* lb0 = &Bs[(wave * 32) * 32];
    u16* lb1 = &Bs[(wave * 32 + 16) * 32];

    const int acol = (kq ^ ((lrow >> 1) & 3)) * 8;  // swizzled k-segment for fragment reads

    v4f acc[4][4];
#pragma unroll
    for (int i = 0; i < 4; i++)
#pragma unroll
        for (int j = 0; j < 4; j++) acc[i][j] = (v4f){0.f, 0.f, 0.f, 0.f};

    for (int k0 = 0; k0 < K; k0 += 32) {
        gl2lds16(a0 + k0, la0);
        gl2lds16(a1 + k0, la1);
        gl2lds16(b0 + k0, lb0);
        gl2lds16(b1 + k0, lb1);
        __syncthreads();

        short8 af[4], bf[4];
#pragma unroll
        for (int i = 0; i < 4; i++)
            af[i] = *(const short8*)&As[(wm * 64 + i * 16 + lrow) * 32 + acol];
#pragma unroll
        for (int i = 0; i < 4; i++)
            bf[i] = *(const short8*)&Bs[(wn * 64 + i * 16 + lrow) * 32 + acol];
#pragma unroll
        for (int im = 0; im < 4; im++)
#pragma unroll
            for (int in = 0; in < 4; in++)
                acc[im][in] = __builtin_amdgcn_mfma_f32_16x16x32_bf16(af[im], bf[in], acc[im][in], 0, 0, 0);
        __syncthreads();
    }

#pragma unroll
    for (int im = 0; im < 4; im++) {
#pragma unroll
        for (int in = 0; in < 4; in++) {
            long row = m0 + wm * 64 + im * 16 + kq * 4;
            long col = n0 + wn * 64 + in * 16 + lrow;
            float bv = bias ? bias[col] : 0.f;
#pragma unroll
            for (int i = 0; i < 4; i++) {
                float val = acc[im][in][i] + bv;
                long idx = (row + i) * ldc + col;
                if (CMODE == 0) {
                    ((float*)Cptr)[idx] = val;
                } else if (CMODE == 1) {
                    ((u16*)Cptr)[idx] = f2bf(val);
                } else {
                    float sg2 = 1.0f / (1.0f + expf(-val));
                    ((u16*)Cptr)[idx] = f2bf(sg2);
                }
            }
        }
    }
}

// ---------------- kmag[b][h][n] = ||k(row,h)|| ----------------
__global__ __launch_bounds__(256) void kmag_kernel(const u16* __restrict__ kv, float* __restrict__ kmag) {
    int tid = threadIdx.x;
    int wave = tid >> 6, lane = tid & 63;
    long gid = (long)blockIdx.x * 4 + wave;   // 0 .. 16384*16-1
    int row = (int)(gid >> 4);
    int h = (int)(gid & 15);
    float kvl = bf2f(kv[(long)row * 2048 + h * 64 + lane]);
    float ss = kvl * kvl;
#pragma unroll
    for (int m = 32; m > 0; m >>= 1) ss += __shfl_xor(ss, m, 64);
    if (lane == 0) {
        int b = row >> 12;
        int n = row & 4095;
        kmag[((long)b * HH + h) * NSEQ + n] = sqrtf(ss);
    }
}

// ---------------- pyramid: 24-tap merged dilated causal conv; field = v*kmag on the fly ----------------
__global__ __launch_bounds__(512) void pyramid_kernel(const u16* __restrict__ kv,
                                                      const float* __restrict__ kmag,
                                                      const float* __restrict__ coefTab,
                                                      u16* __restrict__ accp) {
    __shared__ u16 lds4[NSEQ * 4];  // 32KB: 4096 rows x 4 channels, bf16
    int blk = blockIdx.x;
    int bh = blk >> 4;       // 0..63 : b*16+h
    int cg = blk & 15;       // channel group of 4
    int hd0 = cg * 4;
    int b = bh >> 4, h = bh & 15;
    int tid = threadIdx.x;

    float cf[24];
#pragma unroll
    for (int i = 0; i < 24; i++) cf[i] = coefTab[h * 24 + i];

    const u16* vsrc = kv + 1024 + h * 64 + hd0;
    const float* km = kmag + (long)bh * NSEQ;
#pragma unroll
    for (int i = 0; i < 8; i++) {
        int n = tid + i * 512;
        ushort4 vv = *(const ushort4*)&vsrc[((long)b * NSEQ + n) * 2048];
        float g = km[n];
        ushort4 fo;
        fo.x = f2bf(bf2f(vv.x) * g);
        fo.y = f2bf(bf2f(vv.y) * g);
        fo.z = f2bf(bf2f(vv.z) * g);
        fo.w = f2bf(bf2f(vv.w) * g);
        *(ushort4*)&lds4[n * 4] = fo;
    }
    __syncthreads();

    u16* dst = accp + (long)bh * NSEQ * HD + hd0;
    for (int i = 0; i < 8; i++) {
        int n = tid + i * 512;
        float ax = 0.f, ay = 0.f, az = 0.f, aw = 0.f;
#pragma unroll
        for (int tp = 0; tp < 24; tp++) {
            int s = SHIFTS[tp];
            if (n >= s) {
                const ushort4 f = *(const ushort4*)&lds4[(n - s) * 4];
                float c = cf[tp];
                ax += c * bf2f(f.x); ay += c * bf2f(f.y);
                az += c * bf2f(f.z); aw += c * bf2f(f.w);
            }
        }
        ushort4 o;
        o.x = f2bf(ax); o.y = f2bf(ay); o.z = f2bf(az); o.w = f2bf(aw);
        *(ushort4*)&dst[(long)n * HD] = o;
    }
}

// ---------------- couple: sparse skips + head coupling + gate -> A3 bf16 ----------------
__global__ __launch_bounds__(256) void couple_kernel(const u16* __restrict__ accp,
                                                     const u16* __restrict__ gate,
                                                     const float* __restrict__ coupS,
                                                     const float* __restrict__ swbuf,
                                                     u16* __restrict__ A3) {
    __shared__ float tmp[DD];
    __shared__ float cp[256];
    int row = blockIdx.x;
    int b = row >> 12;
    int n = row & 4095;
    int tid = threadIdx.x;
    float sw0 = swbuf[0], sw1 = swbuf[1];
    cp[tid] = coupS[tid];

    int e = tid * 4;
    int j = e >> 6;      // head
    int hd = e & 63;
    const u16* base = accp + (((long)b * HH + j) * NSEQ + n) * HD + hd;
    ushort4 v0 = *(const ushort4*)base;
    float vx = bf2f(v0.x), vy = bf2f(v0.y), vz = bf2f(v0.z), vw = bf2f(v0.w);
    if (n >= 512) {
        ushort4 s1 = *(const ushort4*)(base - 512 * HD);
        vx += sw0 * bf2f(s1.x); vy += sw0 * bf2f(s1.y);
        vz += sw0 * bf2f(s1.z); vw += sw0 * bf2f(s1.w);
    }
    if (n >= 1024) {
        ushort4 s2 = *(const ushort4*)(base - 1024 * HD);
        vx += sw1 * bf2f(s2.x); vy += sw1 * bf2f(s2.y);
        vz += sw1 * bf2f(s2.z); vw += sw1 * bf2f(s2.w);
    }
    tmp[e] = vx; tmp[e + 1] = vy; tmp[e + 2] = vz; tmp[e + 3] = vw;
    __syncthreads();

    float ox = 0.f, oy = 0.f, oz = 0.f, ow = 0.f;
#pragma unroll
    for (int jj = 0; jj < 16; jj++) {
        float c = cp[j * 16 + jj];
        ox += c * tmp[jj * 64 + hd];
        oy += c * tmp[jj * 64 + hd + 1];
        oz += c * tmp[jj * 64 + hd + 2];
        ow += c * tmp[jj * 64 + hd + 3];
    }
    const ushort4 g = *(const ushort4*)&gate[(long)row * DD + e];
    ox *= bf2f(g.x); oy *= bf2f(g.y); oz *= bf2f(g.z); ow *= bf2f(g.w);
    ushort4 o;
    o.x = f2bf(ox); o.y = f2bf(oy); o.z = f2bf(oz); o.w = f2bf(ow);
    *(ushort4*)&A3[(long)row * DD + e] = o;
}

// ---------------- launch ----------------
extern "C" void kernel_launch(void* const* d_in, const int* in_sizes, int n_in,
                              void* d_out, int out_size, void* d_ws, size_t ws_size,
                              hipStream_t stream) {
    const float* x        = (const float*)d_in[0];   // [16384][1024]
    const float* Wqkv     = (const float*)d_in[1];   // [1024][3072]
    const float* bqkv     = (const float*)d_in[2];   // [3072]
    const float* Wout     = (const float*)d_in[3];   // [1024][1024]
    const float* bout     = (const float*)d_in[4];   // [1024]
    const float* Wgate    = (const float*)d_in[5];   // [1024][1024]
    const float* bgate    = (const float*)d_in[6];   // [1024]
    const float* scale_g  = (const float*)d_in[7];   // [11][16]
    const float* skip_w   = (const float*)d_in[8];   // [2]
    const float* coupling = (const float*)d_in[9];   // [16][16]

    char* ws = (char*)d_ws;
    size_t off = 0;
    auto alloc = [&](size_t bytes) { char* p = ws + off; off += (bytes + 255) & ~(size_t)255; return p; };

    u16*   kv     = (u16*)alloc((size_t)MROWS * 2048 * 2);        // 67.1 MB (k: cols 0..1023, v: 1024..2047)
    u16*   gate   = (u16*)alloc((size_t)MROWS * DD * 2);          // 33.6 MB
    u16*   accp   = (u16*)alloc((size_t)BB * HH * NSEQ * HD * 2); // 33.6 MB, aliased as xb before pyramid
    u16*   WkvT   = (u16*)alloc((size_t)2048 * 1024 * 2);         // 4.2 MB
    u16*   WgateT = (u16*)alloc((size_t)1024 * 1024 * 2);         // 2.1 MB
    u16*   WoutT  = (u16*)alloc((size_t)1024 * 1024 * 2);         // 2.1 MB
    u16*   WfuseT = (u16*)alloc((size_t)1024 * 1024 * 2);         // 2.1 MB
    u16*   WqC    = (u16*)alloc((size_t)1024 * 1024 * 2);         // 2.1 MB
    float* kmag   = (float*)alloc((size_t)BB * HH * NSEQ * 4);    // 1.0 MB
    float* bfuse  = (float*)alloc(1024 * 4);
    float* coefT  = (float*)alloc(16 * 24 * 4);
    float* coupS  = (float*)alloc(256 * 4);
    float* swbuf  = (float*)alloc(2 * 4);
    u16*   xb     = accp;  // alias: xb (x cast to bf16) dead before pyramid writes accp
    u16*   A3     = kv;    // alias: kv dead after pyramid_kernel
    // total ~148 MB

    // 0) cast x -> bf16
    cast_x_kernel<<<(MROWS * DD) / (256 * 8), 256, 0, stream>>>(x, xb);

    // 1) small prep
    prep_kernel<<<1, 64, 0, stream>>>(scale_g, skip_w, coupling, coefT, coupS, swbuf);
    bfuse_kernel<<<16, 256, 0, stream>>>(bqkv, Wgate, bgate, bfuse);

    // 2) weight transposes/casts (fp32 -> bf16, B^T layout for MFMA)
    transpose_cast<<<dim3(64, 32), dim3(32, 8), 0, stream>>>(Wqkv + 1024, 3072, WkvT, 1024);  // k,v cols
    transpose_cast<<<dim3(32, 32), dim3(32, 8), 0, stream>>>(Wgate, 1024, WgateT, 1024);
    transpose_cast<<<dim3(32, 32), dim3(32, 8), 0, stream>>>(Wout, 1024, WoutT, 1024);
    cast_q_kernel<<<1024, 256, 0, stream>>>(Wqkv, WqC);                                       // q cols, no transpose

    // 3) WfuseT[g][k_in] = sum_j WgateT[g][j] * WqC[k_in][j]  (= (Wqkv_q @ Wgate)^T)
    gemm2<1><<<dim3(8, 8), 256, 0, stream>>>(WgateT, 1024, WqC, 1024, 1024,
                                             (const float*)nullptr, WfuseT, 1024);

    // 4) kv = xb @ Wqkv_kv + bqkv_kv   (bf16 out, N=2048)
    gemm2<1><<<dim3(16, 128), 256, 0, stream>>>(xb, 1024, WkvT, 1024, 1024, bqkv + 1024, kv, 2048);

    // 5) kmag
    kmag_kernel<<<(MROWS * HH) / 4, 256, 0, stream>>>(kv, kmag);

    // 6) gate = sigmoid(xb @ Wfuse + bfuse)  (bf16 out)
    gemm2<2><<<dim3(8, 128), 256, 0, stream>>>(xb, 1024, WfuseT, 1024, 1024, bfuse, gate, 1024);

    // 7) pyramid (field formed on the fly, 24 merged taps) -> accp bf16 (xb dead now)
    pyramid_kernel<<<BB * HH * 16, 512, 0, stream>>>(kv, kmag, coefT, accp);

    // 8) skips + coupling + gating -> A3 bf16 (aliases kv)
    couple_kernel<<<MROWS, 256, 0, stream>>>(accp, gate, coupS, swbuf, A3);

    // 9) out = A3 @ Wout + bout  (bf16 A, fp32 out)
    gemm2<0><<<dim3(8, 128), 256, 0, stream>>>(A3, 1024, WoutT, 1024, 1024, bout, (float*)d_out, 1024);
}

// Round 5
// 540.133 us; speedup vs baseline: 1.3586x; 1.0727x over previous
//
#include <hip/hip_runtime.h>
#include <hip/hip_bf16.h>
#include <math.h>

// Problem constants
#define BB 4
#define NSEQ 4096
#define DD 1024
#define HH 16
#define HD 64
#define MROWS (BB * NSEQ)   // 16384

typedef __attribute__((ext_vector_type(8))) short short8;
typedef float v4f __attribute__((ext_vector_type(4)));
typedef unsigned short u16;

typedef __attribute__((address_space(1))) const void gconst_void;
typedef __attribute__((address_space(3))) void lds_void_t;

__device__ __constant__ int SHIFTS[24] = {0,1,2,3,4,6,8,12,16,24,32,48,64,96,128,192,256,384,512,768,1024,1536,2048,3072};

__device__ inline u16 f2bf(float f) {
    unsigned u = __float_as_uint(f);
    unsigned r = u + 0x7fffu + ((u >> 16) & 1u);
    return (u16)(r >> 16);
}
__device__ inline float bf2f(u16 h) {
    return __uint_as_float(((unsigned)h) << 16);
}
__device__ inline void gl2lds16(const u16* g, u16* l) {
    // async global->LDS DMA, 16B/lane; LDS dest = wave-uniform base + lane*16
    __builtin_amdgcn_global_load_lds((gconst_void*)g, (lds_void_t*)l, 16, 0, 0);
}

// ---------------- prep: merged 24-tap coef table per head, coupling softmax, skip sigmoid ----------------
__global__ void prep_kernel(const float* __restrict__ scale_gain, const float* __restrict__ skip_w,
                            const float* __restrict__ coupling, float* __restrict__ coefTab,
                            float* __restrict__ coupS, float* __restrict__ swbuf) {
    const float D4T[4] = {0.4829629131445341f, 0.8365163037378079f, 0.2241438680420134f, -0.1294095225512604f};
    int t = threadIdx.x;
    if (t < 2) swbuf[t] = 1.0f / (1.0f + expf(-skip_w[t]));
    if (t < 16) {
        float m = -1e30f;
        for (int j = 0; j < 16; j++) m = fmaxf(m, coupling[t * 16 + j]);
        float s = 0.f, e[16];
        for (int j = 0; j < 16; j++) { e[j] = expf(coupling[t * 16 + j] - m); s += e[j]; }
        for (int j = 0; j < 16; j++) coupS[t * 16 + j] = e[j] / s;
        float g[11];
        m = -1e30f;
        for (int j = 0; j < 11; j++) m = fmaxf(m, scale_gain[j * 16 + t]);
        s = 0.f;
        for (int j = 0; j < 11; j++) { g[j] = expf(scale_gain[j * 16 + t] - m); s += g[j]; }
        for (int j = 0; j < 11; j++) g[j] /= s;
        float cf[24];
        for (int i = 0; i < 24; i++) cf[i] = 0.f;
        for (int j = 0; j < 11; j++) {
            int d = 1 << j;
            for (int tt = 0; tt < 4; tt++) {
                int sh = (3 - tt) * d;
                for (int i = 0; i < 24; i++) {
                    if (SHIFTS[i] == sh) { cf[i] += g[j] * D4T[tt]; break; }
                }
            }
        }
        for (int i = 0; i < 24; i++) coefTab[t * 24 + i] = cf[i];
    }
}

// ---------------- bfuse[n] = bqkv_q @ Wgate + bgate (fp32) ----------------
__global__ __launch_bounds__(256) void bfuse_kernel(const float* __restrict__ bqkv, const float* __restrict__ Wgate,
                                                    const float* __restrict__ bgate, float* __restrict__ bfuse) {
    __shared__ float part[4][64];
    int nloc = threadIdx.x & 63, strip = threadIdx.x >> 6;
    int n = blockIdx.x * 64 + nloc;
    float s = 0.f;
    for (int j = strip * 256; j < strip * 256 + 256; j++)
        s += bqkv[j] * Wgate[(long)j * 1024 + n];
    part[strip][nloc] = s;
    __syncthreads();
    if (strip == 0)
        bfuse[n] = bgate[n] + part[0][nloc] + part[1][nloc] + part[2][nloc] + part[3][nloc];
}

// ---------------- cast x fp32 -> bf16 ----------------
__global__ __launch_bounds__(256) void cast_x_kernel(const float* __restrict__ x, u16* __restrict__ xb) {
    long i = ((long)blockIdx.x * 256 + threadIdx.x) * 8;
    float4 f0 = *(const float4*)&x[i];
    float4 f1 = *(const float4*)&x[i + 4];
    u16 o[8];
    o[0] = f2bf(f0.x); o[1] = f2bf(f0.y); o[2] = f2bf(f0.z); o[3] = f2bf(f0.w);
    o[4] = f2bf(f1.x); o[5] = f2bf(f1.y); o[6] = f2bf(f1.z); o[7] = f2bf(f1.w);
    *(uint4*)&xb[i] = *(uint4*)o;
}

// ---------------- transpose + cast: W fp32 [rows][ldw] -> WT bf16 [cols][ldt] ----------------
__global__ __launch_bounds__(256) void transpose_cast(const float* __restrict__ W, long ldw,
                                                      u16* __restrict__ WT, long ldt) {
    __shared__ float tile[32][33];
    int tx = threadIdx.x, ty = threadIdx.y;    // 32 x 8
    long x = (long)blockIdx.x * 32 + tx;
    long y0 = (long)blockIdx.y * 32;
    for (int r = 0; r < 32; r += 8)
        tile[ty + r][tx] = W[(y0 + ty + r) * ldw + x];
    __syncthreads();
    for (int r = 0; r < 32; r += 8)
        WT[((long)blockIdx.x * 32 + ty + r) * ldt + y0 + tx] = f2bf(tile[tx][ty + r]);
}

// ---------------- cast q-columns of Wqkv (fp32, ld 3072) -> WqC bf16 [1024][1024] ----------------
__global__ __launch_bounds__(256) void cast_q_kernel(const float* __restrict__ Wqkv, u16* __restrict__ WqC) {
    long i = ((long)blockIdx.x * 256 + threadIdx.x) * 4;
    int row = (int)(i >> 10);
    int col = (int)(i & 1023);
    float4 f = *(const float4*)&Wqkv[(long)row * 3072 + col];
    ushort4 o;
    o.x = f2bf(f.x); o.y = f2bf(f.y); o.z = f2bf(f.z); o.w = f2bf(f.w);
    *(ushort4*)&WqC[i] = o;
}

// ======== GEMM core (shared macro body): 128x128 tile, 4 waves, swizzled LDS, gl2lds staging ========
#define GEMM_PRE()                                                                  \
    __shared__ u16 As[128 * 32];                                                    \
    __shared__ u16 Bs[128 * 32];                                                    \
    const int tid = threadIdx.x;                                                    \
    const int wave = tid >> 6, lane = tid & 63;                                     \
    const int wm = wave >> 1, wn = wave & 1;                                        \
    const int lrow = lane & 15, kq = lane >> 4;                                     \
    const long m0 = (long)blockIdx.y * 128, n0 = (long)blockIdx.x * 128;            \
    const int r0 = wave * 32 + (lane >> 2);                                         \
    const int sg = (lane & 3) ^ ((r0 >> 1) & 3);                                    \
    const u16* a0 = A + (m0 + r0) * lda + sg * 8;                                   \
    const u16* a1 = a0 + 16 * lda;                                                  \
    const u16* b0 = BT + (n0 + r0) * ldb + sg * 8;                                  \
    const u16* b1 = b0 + 16 * ldb;                                                  \
    u16* la0 = &As[(wave * 32) * 32];                                               \
    u16* la1 = &As[(wave * 32 + 16) * 32];                                          \
    u16* lb0 = &Bs[(wave * 32) * 32];                                               \
    u16* lb1 = &Bs[(wave * 32 + 16) * 32];                                          \
    const int acol = (kq ^ ((lrow >> 1) & 3)) * 8;                                  \
    v4f acc[4][4];                                                                  \
    _Pragma("unroll") for (int i = 0; i < 4; i++)                                   \
        _Pragma("unroll") for (int j = 0; j < 4; j++)                               \
            acc[i][j] = (v4f){0.f, 0.f, 0.f, 0.f};                                  \
    for (int k0 = 0; k0 < K; k0 += 32) {                                            \
        gl2lds16(a0 + k0, la0);                                                     \
        gl2lds16(a1 + k0, la1);                                                     \
        gl2lds16(b0 + k0, lb0);                                                     \
        gl2lds16(b1 + k0, lb1);                                                     \
        __syncthreads();                                                            \
        short8 af[4], bf[4];                                                        \
        _Pragma("unroll") for (int i = 0; i < 4; i++)                               \
            af[i] = *(const short8*)&As[(wm * 64 + i * 16 + lrow) * 32 + acol];     \
        _Pragma("unroll") for (int i = 0; i < 4; i++)                               \
            bf[i] = *(const short8*)&Bs[(wn * 64 + i * 16 + lrow) * 32 + acol];     \
        _Pragma("unroll") for (int im = 0; im < 4; im++)                            \
            _Pragma("unroll") for (int in = 0; in < 4; in++)                        \
                acc[im][in] = __builtin_amdgcn_mfma_f32_16x16x32_bf16(af[im], bf[in], acc[im][in], 0, 0, 0); \
        __syncthreads();                                                            \
    }

// ---------------- gemm2: single-output variant ----------------
// CMODE: 0 = fp32 out, 1 = bf16 out
template <int CMODE>
__global__ __launch_bounds__(256) void gemm2(const u16* __restrict__ A, long lda,
                                             const u16* __restrict__ BT, long ldb, int K,
                                             const float* __restrict__ bias,
                                             void* __restrict__ Cptr, long ldc) {
    GEMM_PRE()
#pragma unroll
    for (int im = 0; im < 4; im++) {
#pragma unroll
        for (int in = 0; in < 4; in++) {
            long row = m0 + wm * 64 + im * 16 + kq * 4;
            long col = n0 + wn * 64 + in * 16 + lrow;
            float bv = bias ? bias[col] : 0.f;
#pragma unroll
            for (int i = 0; i < 4; i++) {
                float val = acc[im][in][i] + bv;
                long idx = (row + i) * ldc + col;
                if (CMODE == 0) ((float*)Cptr)[idx] = val;
                else            ((u16*)Cptr)[idx] = f2bf(val);
            }
        }
    }
}

// ---------------- gemm_fused: N=3072; cols 0..2047 -> kv (bf16,+bqkv_kv); 2048.. -> gate (sigmoid,+bfuse) ----------------
__global__ __launch_bounds__(256) void gemm_fused(const u16* __restrict__ A, long lda,
                                                  const u16* __restrict__ BT, long ldb, int K,
                                                  const float* __restrict__ bqkv_kv,
                                                  const float* __restrict__ bfuse,
                                                  u16* __restrict__ kvC, u16* __restrict__ gateC) {
    GEMM_PRE()
    const bool isGate = (n0 >= 2048);
#pragma unroll
    for (int im = 0; im < 4; im++) {
#pragma unroll
        for (int in = 0; in < 4; in++) {
            long row = m0 + wm * 64 + im * 16 + kq * 4;
            long col = n0 + wn * 64 + in * 16 + lrow;
            if (!isGate) {
                float bv = bqkv_kv[col];
#pragma unroll
                for (int i = 0; i < 4; i++)
                    kvC[(row + i) * 2048 + col] = f2bf(acc[im][in][i] + bv);
            } else {
                long gc = col - 2048;
                float bv = bfuse[gc];
#pragma unroll
                for (int i = 0; i < 4; i++) {
                    float sgm = 1.0f / (1.0f + expf(-(acc[im][in][i] + bv)));
                    gateC[(row + i) * 1024 + gc] = f2bf(sgm);
                }
            }
        }
    }
}

// ---------------- kmag[bh][n] = ||k(row,h)|| ----------------
__global__ __launch_bounds__(256) void kmag_kernel(const u16* __restrict__ kv, float* __restrict__ kmag) {
    int tid = threadIdx.x;
    int wave = tid >> 6, lane = tid & 63;
    long gid = (long)blockIdx.x * 4 + wave;   // 0 .. 16384*16-1
    int row = (int)(gid >> 4);
    int h = (int)(gid & 15);
    float kvl = bf2f(kv[(long)row * 2048 + h * 64 + lane]);
    float ss = kvl * kvl;
#pragma unroll
    for (int m = 32; m > 0; m >>= 1) ss += __shfl_xor(ss, m, 64);
    if (lane == 0) {
        int b = row >> 12;
        int n = row & 4095;
        kmag[((long)b * HH + h) * NSEQ + n] = sqrtf(ss);
    }
}

// ---------------- foldv: field_t[bh][cg][n][4] = v * kmag, transposed via LDS tile ----------------
__global__ __launch_bounds__(256) void foldv_kernel(const u16* __restrict__ kv,
                                                    const float* __restrict__ kmag,
                                                    u16* __restrict__ field_t) {
    __shared__ u16 tile[64][72];   // pad 72: 144B row stride (16B-aligned, 4-bank rotation)
    int bh = blockIdx.y;           // 0..63
    int n0 = blockIdx.x * 64;      // 0..4032
    int b = bh >> 4, h = bh & 15;
    int t = threadIdx.x;

    // phase 1: read v rows (coalesced 128B per 4 lanes), scale by kmag, store to LDS tile
    {
        int r = t >> 2;            // row within tile (0..63)
        int c0 = (t & 3) * 16;     // 16 channels
        int n = n0 + r;
        const u16* src = kv + ((long)(b * NSEQ + n)) * 2048 + 1024 + h * 64 + c0;
        uint4 u0 = *(const uint4*)src;
        uint4 u1 = *(const uint4*)(src + 8);
        float km = kmag[(long)bh * NSEQ + n];
        u16 in[16], o[16];
        *(uint4*)&in[0] = u0;
        *(uint4*)&in[8] = u1;
#pragma unroll
        for (int i = 0; i < 16; i++) o[i] = f2bf(bf2f(in[i]) * km);
        *(uint4*)&tile[r][c0] = *(uint4*)&o[0];
        *(uint4*)&tile[r][c0 + 8] = *(uint4*)&o[8];
    }
    __syncthreads();

    // phase 2: write interleaved [cg][n][4] chunks (coalesced 32B/lane)
    {
        int cg = t >> 4;           // 0..15
        int q = t & 15;            // 0..15 -> 4 rows each
        u16 o[16];
#pragma unroll
        for (int j = 0; j < 4; j++) {
            int r = q * 4 + j;
            *(ushort4*)&o[j * 4] = *(const ushort4*)&tile[r][cg * 4];
        }
        u16* dst = field_t + (((long)bh * 16 + cg) * NSEQ + n0 + q * 4) * 4;
        *(uint4*)&dst[0] = *(uint4*)&o[0];
        *(uint4*)&dst[8] = *(uint4*)&o[8];
    }
}

// ---------------- pyramid: 24-tap merged dilated causal conv from field_t ----------------
__global__ __launch_bounds__(512) void pyramid_kernel(const u16* __restrict__ field_t,
                                                      const float* __restrict__ coefTab,
                                                      u16* __restrict__ accp) {
    __shared__ u16 lds4[NSEQ * 4];  // 32KB: 4096 rows x 4 channels, bf16
    int blk = blockIdx.x;
    int bh = blk >> 4;       // 0..63 : b*16+h
    int cg = blk & 15;       // channel group of 4
    int hd0 = cg * 4;
    int h = bh & 15;
    int tid = threadIdx.x;

    float cf[24];
#pragma unroll
    for (int i = 0; i < 24; i++) cf[i] = coefTab[h * 24 + i];

    // stage: contiguous 32 KB copy (fully coalesced 16B per lane)
    const u16* src = field_t + ((long)bh * 16 + cg) * NSEQ * 4;
#pragma unroll
    for (int k = 0; k < 4; k++) {
        long e = ((long)k * 512 + tid) * 8;
        *(uint4*)&lds4[e] = *(const uint4*)&src[e];
    }
    __syncthreads();

    u16* dst = accp + (long)bh * NSEQ * HD + hd0;
    for (int i = 0; i < 8; i++) {
        int n = tid + i * 512;
        float ax = 0.f, ay = 0.f, az = 0.f, aw = 0.f;
#pragma unroll
        for (int tp = 0; tp < 24; tp++) {
            int s = SHIFTS[tp];
            if (n >= s) {
                const ushort4 f = *(const ushort4*)&lds4[(n - s) * 4];
                float c = cf[tp];
                ax += c * bf2f(f.x); ay += c * bf2f(f.y);
                az += c * bf2f(f.z); aw += c * bf2f(f.w);
            }
        }
        ushort4 o;
        o.x = f2bf(ax); o.y = f2bf(ay); o.z = f2bf(az); o.w = f2bf(aw);
        *(ushort4*)&dst[(long)n * HD] = o;
    }
}

// ---------------- couple: sparse skips + head coupling + gate -> A3 bf16 ----------------
__global__ __launch_bounds__(256) void couple_kernel(const u16* __restrict__ accp,
                                                     const u16* __restrict__ gate,
                                                     const float* __restrict__ coupS,
                                                     const float* __restrict__ swbuf,
                                                     u16* __restrict__ A3) {
    __shared__ float tmp[DD];
    __shared__ float cp[256];
    int row = blockIdx.x;
    int b = row >> 12;
    int n = row & 4095;
    int tid = threadIdx.x;
    float sw0 = swbuf[0], sw1 = swbuf[1];
    cp[tid] = coupS[tid];

    int e = tid * 4;
    int j = e >> 6;      // head
    int hd = e & 63;
    const u16* base = accp + (((long)b * HH + j) * NSEQ + n) * HD + hd;
    ushort4 v0 = *(const ushort4*)base;
    float vx = bf2f(v0.x), vy = bf2f(v0.y), vz = bf2f(v0.z), vw = bf2f(v0.w);
    if (n >= 512) {
        ushort4 s1 = *(const ushort4*)(base - 512 * HD);
        vx += sw0 * bf2f(s1.x); vy += sw0 * bf2f(s1.y);
        vz += sw0 * bf2f(s1.z); vw += sw0 * bf2f(s1.w);
    }
    if (n >= 1024) {
        ushort4 s2 = *(const ushort4*)(base - 1024 * HD);
        vx += sw1 * bf2f(s2.x); vy += sw1 * bf2f(s2.y);
        vz += sw1 * bf2f(s2.z); vw += sw1 * bf2f(s2.w);
    }
    tmp[e] = vx; tmp[e + 1] = vy; tmp[e + 2] = vz; tmp[e + 3] = vw;
    __syncthreads();

    float ox = 0.f, oy = 0.f, oz = 0.f, ow = 0.f;
#pragma unroll
    for (int jj = 0; jj < 16; jj++) {
        float c = cp[j * 16 + jj];
        ox += c * tmp[jj * 64 + hd];
        oy += c * tmp[jj * 64 + hd + 1];
        oz += c * tmp[jj * 64 + hd + 2];
        ow += c * tmp[jj * 64 + hd + 3];
    }
    const ushort4 g = *(const ushort4*)&gate[(long)row * DD + e];
    ox *= bf2f(g.x); oy *= bf2f(g.y); oz *= bf2f(g.z); ow *= bf2f(g.w);
    ushort4 o;
    o.x = f2bf(ox); o.y = f2bf(oy); o.z = f2bf(oz); o.w = f2bf(ow);
    *(ushort4*)&A3[(long)row * DD + e] = o;
}

// ---------------- launch ----------------
extern "C" void kernel_launch(void* const* d_in, const int* in_sizes, int n_in,
                              void* d_out, int out_size, void* d_ws, size_t ws_size,
                              hipStream_t stream) {
    const float* x        = (const float*)d_in[0];   // [16384][1024]
    const float* Wqkv     = (const float*)d_in[1];   // [1024][3072]
    const float* bqkv     = (const float*)d_in[2];   // [3072]
    const float* Wout     = (const float*)d_in[3];   // [1024][1024]
    const float* bout     = (const float*)d_in[4];   // [1024]
    const float* Wgate    = (const float*)d_in[5];   // [1024][1024]
    const float* bgate    = (const float*)d_in[6];   // [1024]
    const float* scale_g  = (const float*)d_in[7];   // [11][16]
    const float* skip_w   = (const float*)d_in[8];   // [2]
    const float* coupling = (const float*)d_in[9];   // [16][16]

    char* ws = (char*)d_ws;
    size_t off = 0;
    auto alloc = [&](size_t bytes) { char* p = ws + off; off += (bytes + 255) & ~(size_t)255; return p; };

    u16*   kv      = (u16*)alloc((size_t)MROWS * 2048 * 2);         // 67.1 MB (k: cols 0..1023, v: 1024..2047)
    u16*   gate    = (u16*)alloc((size_t)MROWS * DD * 2);           // 33.6 MB
    u16*   field_t = (u16*)alloc((size_t)BB * HH * NSEQ * HD * 2);  // 33.6 MB (also aliased as xb early)
    u16*   WkvT    = (u16*)alloc((size_t)2048 * 1024 * 2);          // 4.2 MB   } contiguous: fused B^T
    u16*   WfuseT  = (u16*)alloc((size_t)1024 * 1024 * 2);          // 2.1 MB   } rows 2048..3071
    u16*   WgateT  = (u16*)alloc((size_t)1024 * 1024 * 2);          // 2.1 MB
    u16*   WoutT   = (u16*)alloc((size_t)1024 * 1024 * 2);          // 2.1 MB
    u16*   WqC     = (u16*)alloc((size_t)1024 * 1024 * 2);          // 2.1 MB
    float* kmag    = (float*)alloc((size_t)BB * HH * NSEQ * 4);     // 1.0 MB
    float* bfuse   = (float*)alloc(1024 * 4);
    float* coefT   = (float*)alloc(16 * 24 * 4);
    float* coupS   = (float*)alloc(256 * 4);
    float* swbuf   = (float*)alloc(2 * 4);
    // aliases (all within already-counted regions):
    u16*   xb   = field_t;                              // x cast; dead before foldv writes field_t
    u16*   accp = kv;                                   // pyramid out: kv dead after foldv
    u16*   A3   = kv + (size_t)BB * HH * NSEQ * HD;     // second half of kv region
    // total ~147 MB

    // 0) cast x -> bf16
    cast_x_kernel<<<(MROWS * DD) / (256 * 8), 256, 0, stream>>>(x, xb);

    // 1) small prep
    prep_kernel<<<1, 64, 0, stream>>>(scale_g, skip_w, coupling, coefT, coupS, swbuf);
    bfuse_kernel<<<16, 256, 0, stream>>>(bqkv, Wgate, bgate, bfuse);

    // 2) weight transposes/casts (fp32 -> bf16, B^T layout for MFMA)
    transpose_cast<<<dim3(64, 32), dim3(32, 8), 0, stream>>>(Wqkv + 1024, 3072, WkvT, 1024);  // k,v cols
    transpose_cast<<<dim3(32, 32), dim3(32, 8), 0, stream>>>(Wgate, 1024, WgateT, 1024);
    transpose_cast<<<dim3(32, 32), dim3(32, 8), 0, stream>>>(Wout, 1024, WoutT, 1024);
    cast_q_kernel<<<1024, 256, 0, stream>>>(Wqkv, WqC);                                       // q cols, no transpose

    // 3) WfuseT[g][k_in] = sum_j WgateT[g][j] * WqC[k_in][j]  (= (Wqkv_q @ Wgate)^T)
    gemm2<1><<<dim3(8, 8), 256, 0, stream>>>(WgateT, 1024, WqC, 1024, 1024,
                                             (const float*)nullptr, WfuseT, 1024);

    // 4) fused: [kv | gate] = xb @ [Wkv | Wfuse] (+bias; sigmoid on gate part)
    gemm_fused<<<dim3(24, 128), 256, 0, stream>>>(xb, 1024, WkvT, 1024, 1024,
                                                  bqkv + 1024, bfuse, kv, gate);

    // 5) kmag
    kmag_kernel<<<(MROWS * HH) / 4, 256, 0, stream>>>(kv, kmag);

    // 6) foldv: field_t[bh][cg][n][4] = v * kmag  (xb dead now)
    foldv_kernel<<<dim3(64, 64), 256, 0, stream>>>(kv, kmag, field_t);

    // 7) pyramid (24 merged taps) -> accp (kv region; kv dead)
    pyramid_kernel<<<BB * HH * 16, 512, 0, stream>>>(field_t, coefT, accp);

    // 8) skips + coupling + gating -> A3 (upper half of kv region)
    couple_kernel<<<MROWS, 256, 0, stream>>>(accp, gate, coupS, swbuf, A3);

    // 9) out = A3 @ Wout + bout  (fp32 out)
    gemm2<0><<<dim3(8, 128), 256, 0, stream>>>(A3, 1024, WoutT, 1024, 1024, bout, (float*)d_out, 1024);
}